// Round 2
// baseline (285.863 us; speedup 1.0000x reference)
//
#include <hip/hip_runtime.h>

// Squared Euclidean distance: out[i][j] = ||a_i||^2 + ||b_j||^2 - 2 a_i.b_j
// a: [8192,128] fp32, b: [8192,128] fp32, out: [8192,8192] fp32 (256 MiB).
//
// R1 post-mortem: in-block fp32->bf16 conversion was VALU-bound (each element
// converted 64x, ~512 VALU insts/thread). Fix: pre-convert to bf16 ONCE in a
// prep kernel (fused with exact fp32 norms) into d_ws, then run the m97-style
// GEMM: global_load_lds(16B) staging, ds_read_b128 fragments, MFMA, fused
// epilogue. Target: write-bound, 256 MiB / ~6 TB/s ~ 45 us + ramp.

typedef __attribute__((ext_vector_type(8))) short bf16x8;   // 8 bf16 = 4 VGPRs
typedef __attribute__((ext_vector_type(4))) float f32x4;    // MFMA acc

typedef __attribute__((address_space(1))) const void gvoid_t;
typedef __attribute__((address_space(3))) void lvoid_t;

// fp32 -> bf16 round-to-nearest-even (bit pattern in a ushort)
__device__ __forceinline__ unsigned short f2bf(float f) {
    union { float f; unsigned u; } x; x.f = f;
    unsigned r = x.u + 0x7FFFu + ((x.u >> 16) & 1u);
    return (unsigned short)(r >> 16);
}

// ---------------- kernel 1: convert to bf16 + exact fp32 row norms ----------
// one wave per row of 128 floats: lane reads float2, writes ushort2 (bf16),
// shuffle-reduces the squared norm.
__global__ void prep_kernel(const float* __restrict__ m1,
                            const float* __restrict__ m2,
                            unsigned short* __restrict__ A2,
                            unsigned short* __restrict__ B2,
                            float* __restrict__ n1,
                            float* __restrict__ n2,
                            int rows1, int rows2) {
    int gwave = (int)((blockIdx.x * blockDim.x + threadIdx.x) >> 6);
    int lane  = threadIdx.x & 63;
    const float* src; unsigned short* dst; float* nd; int row;
    if (gwave < rows1) { src = m1; dst = A2; nd = n1; row = gwave; }
    else {
        row = gwave - rows1;
        if (row >= rows2) return;
        src = m2; dst = B2; nd = n2;
    }
    float2 v = ((const float2*)(src + (size_t)row * 128))[lane];
    float s = v.x * v.x + v.y * v.y;
    ushort2 w; w.x = f2bf(v.x); w.y = f2bf(v.y);
    ((ushort2*)(dst + (size_t)row * 128))[lane] = w;
#pragma unroll
    for (int off = 32; off; off >>= 1) s += __shfl_xor(s, off, 64);
    if (lane == 0) nd[row] = s;
}

// ---------------- kernel 2: bf16 MFMA cross-term + fused epilogue ----------
#define BM 128
#define BN 128
#define BK 64

__global__ __launch_bounds__(256, 3)
void dist_kernel(const unsigned short* __restrict__ A2,
                 const unsigned short* __restrict__ B2,
                 const float* __restrict__ n1, const float* __restrict__ n2,
                 float* __restrict__ out) {
    // [row][k] bf16, row stride 64 elems = 128 B. Contiguous in the exact
    // lane order global_load_lds deposits (base + lane*16B).
    __shared__ __align__(16) unsigned short As[BM * BK];
    __shared__ __align__(16) unsigned short Bs[BN * BK];

    const int tid  = threadIdx.x;
    const int wave = tid >> 6;          // 0..3
    const int lane = tid & 63;
    const int q    = lane >> 4;         // quad 0..3
    const int l15  = lane & 15;

    const int ti = blockIdx.y * BM;     // rows of mat1
    const int tj = blockIdx.x * BN;     // rows of mat2 (= cols of out)

    const int wm = (wave >> 1) * 64;    // wave's 64x64 sub-tile
    const int wn = (wave & 1) * 64;

    const int srow   = lane >> 3;       // 0..7: row within a 1KiB staging instr
    const int schunk = lane & 7;        // 16B chunk within the 128B row

    f32x4 acc[4][4] = {};

    for (int kc = 0; kc < 128; kc += BK) {
        // ---- stage A tile: 16 instrs x 1 KiB; 4 per wave ----
#pragma unroll
        for (int t = 0; t < 4; ++t) {
            int i = wave * 4 + t;                     // instr index, wave-uniform
            int row = i * 8 + srow;
            const unsigned short* g = A2 + (size_t)(ti + row) * 128 + kc + schunk * 8;
            unsigned short* l = As + i * 512;         // lane lands at +lane*16B
            __builtin_amdgcn_global_load_lds((gvoid_t*)g, (lvoid_t*)l, 16, 0, 0);
        }
        // ---- stage B tile ----
#pragma unroll
        for (int t = 0; t < 4; ++t) {
            int i = wave * 4 + t;
            int row = i * 8 + srow;
            const unsigned short* g = B2 + (size_t)(tj + row) * 128 + kc + schunk * 8;
            unsigned short* l = Bs + i * 512;
            __builtin_amdgcn_global_load_lds((gvoid_t*)g, (lvoid_t*)l, 16, 0, 0);
        }
        __syncthreads();

        // ---- MFMA over this K chunk ----
        // A frag: lane holds A[m=l15][k=q*8+j]; B frag: B[n=l15][k=q*8+j]
#pragma unroll
        for (int kk = 0; kk < BK; kk += 32) {
            bf16x8 af[4], bfr[4];
#pragma unroll
            for (int mi = 0; mi < 4; ++mi)
                af[mi] = *(const bf16x8*)&As[(wm + mi * 16 + l15) * BK + kk + q * 8];
#pragma unroll
            for (int ni = 0; ni < 4; ++ni)
                bfr[ni] = *(const bf16x8*)&Bs[(wn + ni * 16 + l15) * BK + kk + q * 8];
#pragma unroll
            for (int mi = 0; mi < 4; ++mi)
#pragma unroll
                for (int ni = 0; ni < 4; ++ni)
                    acc[mi][ni] = __builtin_amdgcn_mfma_f32_16x16x32_bf16(
                        af[mi], bfr[ni], acc[mi][ni], 0, 0, 0);
        }
        __syncthreads();
    }

    // ---- epilogue: out = n1[r] + n2[c] - 2*cross ----
    // C/D layout: col = l15, row = q*4 + reg (verified R1: absmax 2.0 passed)
#pragma unroll
    for (int mi = 0; mi < 4; ++mi) {
        int r0 = ti + wm + mi * 16 + q * 4;
        float a0 = n1[r0 + 0], a1 = n1[r0 + 1], a2 = n1[r0 + 2], a3 = n1[r0 + 3];
#pragma unroll
        for (int ni = 0; ni < 4; ++ni) {
            int c = tj + wn + ni * 16 + l15;
            float nb = n2[c];
            f32x4 v = acc[mi][ni];
            out[(size_t)(r0 + 0) * 8192 + c] = a0 + nb - 2.0f * v[0];
            out[(size_t)(r0 + 1) * 8192 + c] = a1 + nb - 2.0f * v[1];
            out[(size_t)(r0 + 2) * 8192 + c] = a2 + nb - 2.0f * v[2];
            out[(size_t)(r0 + 3) * 8192 + c] = a3 + nb - 2.0f * v[3];
        }
    }
}

extern "C" void kernel_launch(void* const* d_in, const int* in_sizes, int n_in,
                              void* d_out, int out_size, void* d_ws, size_t ws_size,
                              hipStream_t stream) {
    const float* m1 = (const float*)d_in[0];
    const float* m2 = (const float*)d_in[1];
    float* out = (float*)d_out;
    const int rows1 = in_sizes[0] / 128;   // 8192
    const int rows2 = in_sizes[1] / 128;   // 8192

    // workspace layout: n1 | n2 | A2 (bf16) | B2 (bf16)   (~4.3 MiB total)
    float* n1 = (float*)d_ws;
    float* n2 = n1 + rows1;
    unsigned short* A2 = (unsigned short*)(n2 + rows2);
    unsigned short* B2 = A2 + (size_t)rows1 * 128;

    int total_waves = rows1 + rows2;
    int nb = (total_waves * 64 + 255) / 256;
    prep_kernel<<<nb, 256, 0, stream>>>(m1, m2, A2, B2, n1, n2, rows1, rows2);

    dim3 grid(rows2 / BN, rows1 / BM);
    dist_kernel<<<grid, 256, 0, stream>>>(A2, B2, n1, n2, out);
}

// Round 3
// 276.167 us; speedup vs baseline: 1.0351x; 1.0351x over previous
//
#include <hip/hip_runtime.h>

// Squared Euclidean distance: out[i][j] = ||a_i||^2 + ||b_j||^2 - 2 a_i.b_j
// a: [8192,128] fp32, b: [8192,128] fp32, out: [8192,8192] fp32 (256 MiB).
//
// R2 post-mortem: removing the in-loop fp32->bf16 conversion was NEUTRAL ->
// epilogue-store-bound. R2 wrote via 64 global_store_dword/thread (4 B/lane,
// 64 B segments). Fix: SWAP the MFMA operands (B rows as A-operand) so
// D = cross[j][i]; then reg index = consecutive out COLUMNS -> direct
// global_store_dwordx4 (16 B/lane, 16 stores/thread, 4x fewer store instrs).

typedef __attribute__((ext_vector_type(8))) short bf16x8;   // 8 bf16 = 4 VGPRs
typedef __attribute__((ext_vector_type(4))) float f32x4;    // MFMA acc

typedef __attribute__((address_space(1))) const void gvoid_t;
typedef __attribute__((address_space(3))) void lvoid_t;

// fp32 -> bf16 round-to-nearest-even (bit pattern in a ushort)
__device__ __forceinline__ unsigned short f2bf(float f) {
    union { float f; unsigned u; } x; x.f = f;
    unsigned r = x.u + 0x7FFFu + ((x.u >> 16) & 1u);
    return (unsigned short)(r >> 16);
}

// ---------------- kernel 1: convert to bf16 + exact fp32 row norms ----------
__global__ void prep_kernel(const float* __restrict__ m1,
                            const float* __restrict__ m2,
                            unsigned short* __restrict__ A2,
                            unsigned short* __restrict__ B2,
                            float* __restrict__ n1,
                            float* __restrict__ n2,
                            int rows1, int rows2) {
    int gwave = (int)((blockIdx.x * blockDim.x + threadIdx.x) >> 6);
    int lane  = threadIdx.x & 63;
    const float* src; unsigned short* dst; float* nd; int row;
    if (gwave < rows1) { src = m1; dst = A2; nd = n1; row = gwave; }
    else {
        row = gwave - rows1;
        if (row >= rows2) return;
        src = m2; dst = B2; nd = n2;
    }
    float2 v = ((const float2*)(src + (size_t)row * 128))[lane];
    float s = v.x * v.x + v.y * v.y;
    ushort2 w; w.x = f2bf(v.x); w.y = f2bf(v.y);
    ((ushort2*)(dst + (size_t)row * 128))[lane] = w;
#pragma unroll
    for (int off = 32; off; off >>= 1) s += __shfl_xor(s, off, 64);
    if (lane == 0) nd[row] = s;
}

// ---------------- kernel 2: bf16 MFMA cross-term + fused epilogue ----------
#define BM 128
#define BN 128
#define BK 64

__global__ __launch_bounds__(256, 3)
void dist_kernel(const unsigned short* __restrict__ A2,
                 const unsigned short* __restrict__ B2,
                 const float* __restrict__ n1, const float* __restrict__ n2,
                 float* __restrict__ out) {
    // [row][k] bf16, row stride 64 elems = 128 B; contiguous in the exact
    // lane order global_load_lds deposits (base + lane*16B).
    __shared__ __align__(16) unsigned short As[BM * BK];
    __shared__ __align__(16) unsigned short Bs[BN * BK];

    const int tid  = threadIdx.x;
    const int wave = tid >> 6;          // 0..3
    const int lane = tid & 63;
    const int q    = lane >> 4;         // quad 0..3
    const int l15  = lane & 15;

    const int ti = blockIdx.y * BM;     // rows of mat1 (out rows)
    const int tj = blockIdx.x * BN;     // rows of mat2 (out cols)

    const int wi = (wave >> 1) * 64;    // wave's 64 (out-row) x 64 (out-col) tile
    const int wj = (wave & 1) * 64;

    const int srow   = lane >> 3;       // 0..7: row within a 1KiB staging instr
    const int schunk = lane & 7;        // 16B chunk within the 128B row

    // acc[mj][mi]: D = cross[j][i]; D row (q*4+reg) -> out col, D col (l15) -> out row
    f32x4 acc[4][4] = {};

    for (int kc = 0; kc < 128; kc += BK) {
        // ---- stage A tile: 16 instrs x 1 KiB; 4 per wave ----
#pragma unroll
        for (int t = 0; t < 4; ++t) {
            int i = wave * 4 + t;                     // instr index, wave-uniform
            int row = i * 8 + srow;
            const unsigned short* g = A2 + (size_t)(ti + row) * 128 + kc + schunk * 8;
            unsigned short* l = As + i * 512;
            __builtin_amdgcn_global_load_lds((gvoid_t*)g, (lvoid_t*)l, 16, 0, 0);
        }
        // ---- stage B tile ----
#pragma unroll
        for (int t = 0; t < 4; ++t) {
            int i = wave * 4 + t;
            int row = i * 8 + srow;
            const unsigned short* g = B2 + (size_t)(tj + row) * 128 + kc + schunk * 8;
            unsigned short* l = Bs + i * 512;
            __builtin_amdgcn_global_load_lds((gvoid_t*)g, (lvoid_t*)l, 16, 0, 0);
        }
        __syncthreads();

        // ---- MFMA: B rows as the A-operand, A rows as the B-operand ----
        // A-op frag: lane holds Bop[m=l15][k=q*8+..]; B-op frag: Aop[n=l15][k=..]
#pragma unroll
        for (int kk = 0; kk < BK; kk += 32) {
            bf16x8 jf[4], itf[4];
#pragma unroll
            for (int x = 0; x < 4; ++x)
                jf[x] = *(const bf16x8*)&Bs[(wj + x * 16 + l15) * BK + kk + q * 8];
#pragma unroll
            for (int x = 0; x < 4; ++x)
                itf[x] = *(const bf16x8*)&As[(wi + x * 16 + l15) * BK + kk + q * 8];
#pragma unroll
            for (int mj = 0; mj < 4; ++mj)
#pragma unroll
                for (int mi = 0; mi < 4; ++mi)
                    acc[mj][mi] = __builtin_amdgcn_mfma_f32_16x16x32_bf16(
                        jf[mj], itf[mi], acc[mj][mi], 0, 0, 0);
        }
        __syncthreads();
    }

    // ---- epilogue: out[i][j] = n1[i] + n2[j] - 2*cross[j][i] ----
    // lane (q,l15), acc[mj][mi] reg r: j = tj+wj+mj*16+q*4+r (contiguous!),
    // i = ti+wi+mi*16+l15  -> one float4 store per (mj,mi).
#pragma unroll
    for (int mi = 0; mi < 4; ++mi) {
        int i = ti + wi + mi * 16 + l15;
        float na = n1[i];
        float* orow = out + (size_t)i * 8192;
#pragma unroll
        for (int mj = 0; mj < 4; ++mj) {
            int j0 = tj + wj + mj * 16 + q * 4;
            float4 nb = *(const float4*)(n2 + j0);
            f32x4 v = acc[mj][mi];
            float4 o;
            o.x = na + nb.x - 2.0f * v[0];
            o.y = na + nb.y - 2.0f * v[1];
            o.z = na + nb.z - 2.0f * v[2];
            o.w = na + nb.w - 2.0f * v[3];
            *(float4*)(orow + j0) = o;
        }
    }
}

extern "C" void kernel_launch(void* const* d_in, const int* in_sizes, int n_in,
                              void* d_out, int out_size, void* d_ws, size_t ws_size,
                              hipStream_t stream) {
    const float* m1 = (const float*)d_in[0];
    const float* m2 = (const float*)d_in[1];
    float* out = (float*)d_out;
    const int rows1 = in_sizes[0] / 128;   // 8192
    const int rows2 = in_sizes[1] / 128;   // 8192

    // workspace: n1 | n2 | A2 (bf16) | B2 (bf16)   (~4.3 MiB total)
    float* n1 = (float*)d_ws;
    float* n2 = n1 + rows1;
    unsigned short* A2 = (unsigned short*)(n2 + rows2);
    unsigned short* B2 = A2 + (size_t)rows1 * 128;

    int total_waves = rows1 + rows2;
    int nb = (total_waves * 64 + 255) / 256;
    prep_kernel<<<nb, 256, 0, stream>>>(m1, m2, A2, B2, n1, n2, rows1, rows2);

    dim3 grid(rows2 / BN, rows1 / BM);
    dist_kernel<<<grid, 256, 0, stream>>>(A2, B2, n1, n2, out);
}